// Round 6
// baseline (668.862 us; speedup 1.0000x reference)
//
#include <hip/hip_runtime.h>
#include <math.h>

// Problem dims (fixed by reference)
#define S_ 4096
#define B_ 4
#define D_ 1024
#define R_ (S_*B_)   // 16384 rows
#define H_ (4*D_)    // 4096

typedef unsigned short u16;
typedef unsigned int   u32;
typedef __attribute__((ext_vector_type(8))) short bf16x8;   // 8 bf16 in 4 VGPRs
typedef __attribute__((ext_vector_type(4))) float f32x4;
typedef __attribute__((ext_vector_type(16))) float f32x16;

__device__ __forceinline__ u16 f2bf(float f) {
  u32 u = __float_as_uint(f);
  u32 r = (u + 0x7fffu + ((u >> 16) & 1u)) >> 16;   // RNE
  return (u16)r;
}
__device__ __forceinline__ float bf2f(u16 u) {
  return __uint_as_float(((u32)u) << 16);
}

// async global->LDS, 16B per lane; LDS dest is wave-uniform base + lane*16
__device__ __forceinline__ void gl_lds16(const u16* g, u16* l) {
  __builtin_amdgcn_global_load_lds((const __attribute__((address_space(1))) void*)g,
                                   (__attribute__((address_space(3))) void*)l,
                                   16, 0, 0);
}
// raw barrier with compiler memory fence (no implicit vmcnt drain)
__device__ __forceinline__ void BAR() {
  asm volatile("s_barrier" ::: "memory");
}

// fast GELU (tanh form): max |err| ~1e-3, far below bf16 quantum here.
__device__ __forceinline__ float gelu_f(float t) {
  const float u2 = 1.5957691216f * t + 0.0713548162726f * t * t * t;
  return t / (1.0f + __expf(-u2));
}

// ---------------------------------------------------------------------------
// fp32 -> bf16 convert (vector x4)
__global__ __launch_bounds__(256) void f2bf_k(const float* __restrict__ in,
                                              u16* __restrict__ out, int n4) {
  int i = blockIdx.x * 256 + threadIdx.x;
  if (i < n4) {
    float4 v = ((const float4*)in)[i];
    ushort4 o = make_ushort4(f2bf(v.x), f2bf(v.y), f2bf(v.z), f2bf(v.w));
    ((ushort4*)out)[i] = o;
  }
}

// ---------------------------------------------------------------------------
// LayerNorm over D=1024, one row per 256-thread block, 4 elems/thread.
template<bool TR>
__global__ __launch_bounds__(256) void ln_k(const float* __restrict__ x,
                                            u16* __restrict__ o,
                                            const float* __restrict__ g,
                                            const float* __restrict__ bb) {
  const int row = blockIdx.x;
  const int tid = threadIdx.x;
  const float4 v = *(const float4*)&x[(long)row * D_ + tid * 4];
  float vv[4] = {v.x, v.y, v.z, v.w};
  float s = vv[0] + vv[1] + vv[2] + vv[3];
  float q = vv[0]*vv[0] + vv[1]*vv[1] + vv[2]*vv[2] + vv[3]*vv[3];
  const int l = tid & 63, w = tid >> 6;
  #pragma unroll
  for (int off = 32; off > 0; off >>= 1) {
    s += __shfl_down(s, off, 64);
    q += __shfl_down(q, off, 64);
  }
  __shared__ float red[8];
  if (l == 0) { red[w] = s; red[4 + w] = q; }
  __syncthreads();
  s = red[0] + red[1] + red[2] + red[3];
  q = red[4] + red[5] + red[6] + red[7];
  const float m   = s * (1.0f / D_);
  const float var = q * (1.0f / D_) - m * m;
  const float inv = rsqrtf(var + 1e-5f);
  const long orow = TR ? ((long)(row % B_) * S_ + (row / B_)) : (long)row;
  const int j = tid * 4;
  ushort4 ou = make_ushort4(
      f2bf((vv[0] - m) * inv * g[j+0] + bb[j+0]),
      f2bf((vv[1] - m) * inv * g[j+1] + bb[j+1]),
      f2bf((vv[2] - m) * inv * g[j+2] + bb[j+2]),
      f2bf((vv[3] - m) * inv * g[j+3] + bb[j+3]));
  *(ushort4*)&o[orow * D_ + j] = ou;
}

// ---------------------------------------------------------------------------
// column sums of XWv: first[b][d] = sum_n XWv[b][n][d]
__global__ __launch_bounds__(256) void colsum_k(const u16* __restrict__ Xw,
                                                float* __restrict__ first) {
  const int d  = blockIdx.x * 256 + threadIdx.x;
  const int b  = blockIdx.z;
  const int n0 = blockIdx.y * 256;
  const u16* p = Xw + ((long)b * S_ + n0) * D_ + d;
  float s = 0.f;
  #pragma unroll 8
  for (int n = 0; n < 256; ++n) s += bf2f(p[(long)n * D_]);
  atomicAdd(&first[b * D_ + d], s);
}

// ---------------------------------------------------------------------------
// 64x64 bf16 transpose: in [b][S_][D_] -> out [b][D_][S_]
__global__ __launch_bounds__(256) void tr_k(const u16* __restrict__ in,
                                            u16* __restrict__ out) {
  __shared__ u16 t[64][65];
  const int b  = blockIdx.z;
  const int e0 = blockIdx.x * 64;
  const int n0 = blockIdx.y * 64;
  const int tid = threadIdx.x;
  #pragma unroll
  for (int i = 0; i < 4; ++i) {
    const int v = i * 256 + tid;
    const int r = v >> 4;
    const int c = (v & 15) << 2;
    ushort4 d4 = *(const ushort4*)&in[((long)b * S_ + n0 + r) * D_ + e0 + c];
    t[r][c+0] = d4.x; t[r][c+1] = d4.y; t[r][c+2] = d4.z; t[r][c+3] = d4.w;
  }
  __syncthreads();
  #pragma unroll
  for (int i = 0; i < 4; ++i) {
    const int v = i * 256 + tid;
    const int e = v >> 4;
    const int c = (v & 15) << 2;
    ushort4 o4 = make_ushort4(t[c+0][e], t[c+1][e], t[c+2][e], t[c+3][e]);
    *(ushort4*)&out[((long)b * D_ + e0 + e) * S_ + n0 + c] = o4;
  }
}

// ---------------------------------------------------------------------------
// 128x128-tile NT GEMM (kept for Mt: per-batch 1024x1024, K=4096).
template<int EPI>
__global__ __launch_bounds__(256, 2) void gemm_k(
    const u16* __restrict__ A, long sAz,
    const u16* __restrict__ B, long sBz,
    int K, int ldc,
    u16* __restrict__ Cb, long sCz,
    float* __restrict__ Cf,
    const float* __restrict__ vec1,
    float scale)
{
  const int bz = blockIdx.z;
  const u16* Ab = A + (long)bz * sAz;
  const u16* Bb = B + (long)bz * sBz;
  const int row0 = blockIdx.x * 128;
  const int col0 = blockIdx.y * 128;
  const int lda = K;

  __shared__ __align__(16) u16 As[128 * 32];
  __shared__ __align__(16) u16 Bs[128 * 32];

  const int tid = threadIdx.x;
  const int w = tid >> 6;
  const int l = tid & 63;
  const int wr = (w >> 1) * 64;
  const int wc = (w & 1) * 64;

  f32x4 acc[4][4];
  #pragma unroll
  for (int mi = 0; mi < 4; ++mi)
    #pragma unroll
    for (int ni = 0; ni < 4; ++ni) acc[mi][ni] = (f32x4){0.f, 0.f, 0.f, 0.f};

  const int lrow = l & 15;
  const int lo   = l >> 4;

  for (int k0 = 0; k0 < K; k0 += 32) {
    __syncthreads();
    #pragma unroll
    for (int it = 0; it < 2; ++it) {
      const int cb = it * 256 + (w << 6);
      const int c  = cb + l;
      const int r  = c >> 2;
      const int qs = ((c & 3) ^ ((r >> 1) & 3)) << 3;
      gl_lds16(Ab + (long)(row0 + r) * lda + (k0 + qs), &As[cb << 3]);
      gl_lds16(Bb + (long)(col0 + r) * lda + (k0 + qs), &Bs[cb << 3]);
    }
    __syncthreads();

    bf16x8 af[4], bfr[4];
    #pragma unroll
    for (int mi = 0; mi < 4; ++mi) {
      const int R = wr + mi * 16 + lrow;
      af[mi]  = *(const bf16x8*)&As[R * 32 + ((lo ^ ((R >> 1) & 3)) << 3)];
    }
    #pragma unroll
    for (int ni = 0; ni < 4; ++ni) {
      const int R = wc + ni * 16 + lrow;
      bfr[ni] = *(const bf16x8*)&Bs[R * 32 + ((lo ^ ((R >> 1) & 3)) << 3)];
    }
    #pragma unroll
    for (int mi = 0; mi < 4; ++mi)
      #pragma unroll
      for (int ni = 0; ni < 4; ++ni)
        acc[mi][ni] = __builtin_amdgcn_mfma_f32_16x16x32_bf16(af[mi], bfr[ni], acc[mi][ni], 0, 0, 0);
  }

  const int rbase = row0 + wr + (lo << 2);
  const int cbase = col0 + wc + lrow;
  #pragma unroll
  for (int mi = 0; mi < 4; ++mi)
    #pragma unroll
    for (int ni = 0; ni < 4; ++ni)
      #pragma unroll
      for (int r = 0; r < 4; ++r) {
        const int i = rbase + mi * 16 + r;
        const int j = cbase + ni * 16;
        if constexpr (EPI == 0)
          Cb[(long)bz * sCz + (long)i * ldc + j] = f2bf(acc[mi][ni][r]);
      }
  (void)Cf; (void)vec1; (void)scale;
}

// ---------------------------------------------------------------------------
// 256x256-tile NT GEMM, BK=64, 512 threads = 8 waves (2M x 4N), wave tile
// 128x64 = 4x2 positions of 32x32x16 MFMA (2x FLOP per LDS byte vs 16x16x32).
// 2 phases per K-tile (ks-pair per phase), double-buffered 128 KB LDS,
// counted vmcnt(8), setprio MFMA clusters, conflict-free chunk swizzle,
// bijective XCD-aware block swizzle on flattened (x,y).
// C[i,j] = sum_k A[i*K+k]*B[j*K+k].
template<int EPI>
__global__ __launch_bounds__(512, 2) void gemm256_k(
    const u16* __restrict__ A, long sAz,
    const u16* __restrict__ B, long sBz,
    int K, int ldc,
    u16* __restrict__ Cb, long sCz,
    float* __restrict__ Cf,
    const float* __restrict__ vec1,
    float scale)
{
  const int bz = blockIdx.z;
  const u16* Ab = A + (long)bz * sAz;
  const u16* Bb = B + (long)bz * sBz;

  // XCD swizzle (all grids have nxy % 8 == 0): XCD c gets contiguous s-chunk
  const int nbx = gridDim.x;
  const int nxy = nbx * gridDim.y;
  int bid = blockIdx.y * nbx + blockIdx.x;
  bid = (bid & 7) * (nxy >> 3) + (bid >> 3);
  const int row0 = (bid % nbx) * 256;
  const int col0 = (bid / nbx) * 256;

  // [dbuf][khalf][op][256*32]
  __shared__ __align__(16) u16 Lds[2][2][2][256 * 32];

  const int tid = threadIdx.x;
  const int w   = tid >> 6;       // wave 0..7
  const int l   = tid & 63;
  const int wm  = w >> 2;         // 0..1  (row half: 128 rows)
  const int wn  = w & 3;          // 0..3  (col quarter: 64 cols)
  const int l5  = l & 31;
  const int hi  = l >> 5;         // 0..1

  const int NKH = K >> 5;         // number of K-halves (32-k units)
  const int NT  = K >> 6;         // number of K-tiles (64)

  // stage geometry: lane l covers unit row rs = w*32 + i*16 + (l>>2),
  // LDS chunk (l&3); pre-swizzled source chunk = (l&3) ^ ((rs>>1)&3)
  const int rs   = w * 32 + (l >> 2);
  const int qsrc = ((l & 3) ^ ((l >> 3) & 3)) << 3;   // element offset

  auto STAGE = [&](int khg, int op) {
    if (khg >= NKH) return;
    const u16* src = (op ? Bb : Ab) + (long)((op ? col0 : row0) + rs) * K + khg * 32 + qsrc;
    u16* dst = &Lds[(khg >> 1) & 1][khg & 1][op][(w * 2) * 512];
    gl_lds16(src, dst);
    gl_lds16(src + (long)16 * K, dst + 512);
  };

  // frag-read chunk offsets (elements) for ks&1 = 0/1: q = (ks&1)*2 + hi,
  // lds chunk = q ^ ((l5>>1)&3)
  const int key = (l5 >> 1) & 3;
  const int q0  = ((0 + hi) ^ key) << 3;   // ks even
  const int q1  = ((2 + hi) ^ key) << 3;   // ks odd

  f32x16 acc[4][2];
  #pragma unroll
  for (int mi = 0; mi < 4; ++mi)
    #pragma unroll
    for (int ni = 0; ni < 2; ++ni)
      acc[mi][ni] = (f32x16){0.f,0.f,0.f,0.f, 0.f,0.f,0.f,0.f,
                             0.f,0.f,0.f,0.f, 0.f,0.f,0.f,0.f};

  // prologue: stage tiles 0 and 1 completely (8 units, 16 loads/thread)
  STAGE(0, 0); STAGE(0, 1); STAGE(1, 0); STAGE(1, 1);
  STAGE(2, 0); STAGE(2, 1); STAGE(3, 0); STAGE(3, 1);
  asm volatile("s_waitcnt vmcnt(12)" ::: "memory");   // tile-0 kh0 (A,B) landed
  BAR();

  for (int kt = 0; kt < NT; ++kt) {
    const int cur = kt & 1;
    bf16x8 af[4][2], bf[2][2];

    // ================= phase 0: ks 0,1 (kh=0) =================
    {
      const u16* LA = &Lds[cur][0][0][0];
      const u16* LB = &Lds[cur][0][1][0];
      #pragma unroll
      for (int ni = 0; ni < 2; ++ni) {
        const int R = wn * 64 + ni * 32 + l5;
        bf[ni][0] = *(const bf16x8*)&LB[R * 32 + q0];
        bf[ni][1] = *(const bf16x8*)&LB[R * 32 + q1];
      }
      #pragma unroll
      for (int mi = 0; mi < 4; ++mi) {
        const int R = wm * 128 + mi * 32 + l5;
        af[mi][0] = *(const bf16x8*)&LA[R * 32 + q0];
        af[mi][1] = *(const bf16x8*)&LA[R * 32 + q1];
      }
    }
    STAGE(2 * kt + 4, 0); STAGE(2 * kt + 4, 1);       // kh0 of tile kt+2
    if (kt == NT - 1) asm volatile("s_waitcnt vmcnt(4)" ::: "memory");
    else              asm volatile("s_waitcnt vmcnt(8)" ::: "memory");
    BAR();
    __builtin_amdgcn_s_setprio(1);
    #pragma unroll
    for (int mi = 0; mi < 4; ++mi)
      #pragma unroll
      for (int ni = 0; ni < 2; ++ni) {
        acc[mi][ni] = __builtin_amdgcn_mfma_f32_32x32x16_bf16(af[mi][0], bf[ni][0], acc[mi][ni], 0, 0, 0);
        acc[mi][ni] = __builtin_amdgcn_mfma_f32_32x32x16_bf16(af[mi][1], bf[ni][1], acc[mi][ni], 0, 0, 0);
      }
    __builtin_amdgcn_s_setprio(0);
    BAR();

    // ================= phase 1: ks 2,3 (kh=1) =================
    {
      const u16* LA = &Lds[cur][1][0][0];
      const u16* LB = &Lds[cur][1][1][0];
      #pragma unroll
      for (int ni = 0; ni < 2; ++ni) {
        const int R = wn * 64 + ni * 32 + l5;
        bf[ni][0] = *(const bf16x8*)&LB[R * 32 + q0];
        bf[ni][1] = *(const bf16x8*)&LB[R * 32 + q1];
      }
      #pragma unroll
      for (int mi = 0; mi < 4; ++mi) {
        const int R = wm * 128 + mi * 32 + l5;
        af[mi][0] = *(const bf16x8*)&LA[R * 32 + q0];
        af[mi][1] = *(const bf16x8*)&LA[R * 32 + q1];
      }
    }
    STAGE(2 * kt + 5, 0); STAGE(2 * kt + 5, 1);       // kh1 of tile kt+2
    if (kt == NT - 1) asm volatile("s_waitcnt vmcnt(0)" ::: "memory");
    else              asm volatile("s_waitcnt vmcnt(8)" ::: "memory");
    BAR();
    __builtin_amdgcn_s_setprio(1);
    #pragma unroll
    for (int mi = 0; mi < 4; ++mi)
      #pragma unroll
      for (int ni = 0; ni < 2; ++ni) {
        acc[mi][ni] = __builtin_amdgcn_mfma_f32_32x32x16_bf16(af[mi][0], bf[ni][0], acc[mi][ni], 0, 0, 0);
        acc[mi][ni] = __builtin_amdgcn_mfma_f32_32x32x16_bf16(af[mi][1], bf[ni][1], acc[mi][ni], 0, 0, 0);
      }
    __builtin_amdgcn_s_setprio(0);
    BAR();
  }

  // epilogue: 32x32 C/D mapping col=lane&31, row=(reg&3)+8*(reg>>2)+4*(lane>>5)
  const int jb = col0 + wn * 64 + l5;
  #pragma unroll
  for (int mi = 0; mi < 4; ++mi) {
    #pragma unroll
    for (int ni = 0; ni < 2; ++ni) {
      const int j = jb + ni * 32;
      #pragma unroll
      for (int r = 0; r < 16; ++r) {
        const long i = row0 + wm * 128 + mi * 32 + (r & 3) + 8 * (r >> 2) + 4 * hi;
        const float a = acc[mi][ni][r];
        if constexpr (EPI == 0) {
          Cb[(long)bz * sCz + i * ldc + j] = f2bf(a);
        } else if constexpr (EPI == 1) {
          const float xv = bf2f(Ab[i * K + j]);   // K == D_ here
          Cf[(i * B_ + bz) * (long)D_ + j] =
              xv + vec1[bz * D_ + j] * (1.0f / S_) + scale * a;
        } else if constexpr (EPI == 2) {
          Cb[i * ldc + j] = f2bf(gelu_f(a + vec1[j]));
        } else {
          const long idx = i * ldc + j;
          Cf[idx] = Cf[idx] + a + vec1[j];
        }
      }
    }
  }
}

// ---------------------------------------------------------------------------
extern "C" void kernel_launch(void* const* d_in, const int* in_sizes, int n_in,
                              void* d_out, int out_size, void* d_ws, size_t ws_size,
                              hipStream_t stream) {
  (void)in_sizes; (void)n_in; (void)out_size; (void)ws_size;
  const float* x     = (const float*)d_in[0];
  const float* W_v   = (const float*)d_in[1];
  const float* theta = (const float*)d_in[2];
  const float* ln1g  = (const float*)d_in[3];
  const float* ln1b  = (const float*)d_in[4];
  const float* ln2g  = (const float*)d_in[5];
  const float* ln2b  = (const float*)d_in[6];
  const float* w1    = (const float*)d_in[7];
  const float* b1    = (const float*)d_in[8];
  const float* w2    = (const float*)d_in[9];
  const float* b2    = (const float*)d_in[10];
  float* out = (float*)d_out;

  char* ws = (char*)d_ws;
  const size_t MB = 1024ull * 1024ull;
  u16*   Wv_bf = (u16*)(ws + 0);              //  2 MB   (Th must follow contiguously)
  u16*   Th_bf = (u16*)(ws + 2 * MB);         //  2 MB
  u16*   w1_bf = (u16*)(ws + 4 * MB);         //  8 MB
  u16*   w2_bf = (u16*)(ws + 12 * MB);        //  8 MB
  float* first = (float*)(ws + 20 * MB);      // 16 KB
  u16*   Mt    = (u16*)(ws + 21 * MB);        //  8 MB  Mt[b][e][d] = M[b][d][e]
  u16*   Xn    = (u16*)(ws + 29 * MB);        // 32 MB  [B][S][D] (LN1 out, transposed)
  u16*   XWv   = (u16*)(ws + 61 * MB);        // 32 MB  (XWv,Xth contiguous: z-stride)
  u16*   Xth   = (u16*)(ws + 93 * MB);        // 32 MB
  u16*   XWvT  = (u16*)(ws + 125 * MB);       // 32 MB  [B][D][S]
  u16*   XthT  = (u16*)(ws + 157 * MB);       // 32 MB  (ends 189 MB)
  u16*   h2    = (u16*)(ws + 29 * MB);        // 32 MB  (over dead Xn)
  u16*   G     = (u16*)(ws + 61 * MB);        // 128 MB [16384][4096] (over dead XWv..XthT)

  // 1) weights -> bf16
  f2bf_k<<<dim3((D_*D_/4 + 255)/256), 256, 0, stream>>>(W_v,   Wv_bf, D_*D_/4);
  f2bf_k<<<dim3((D_*D_/4 + 255)/256), 256, 0, stream>>>(theta, Th_bf, D_*D_/4);
  f2bf_k<<<dim3((H_*D_/4 + 255)/256), 256, 0, stream>>>(w1,    w1_bf, H_*D_/4);
  f2bf_k<<<dim3((H_*D_/4 + 255)/256), 256, 0, stream>>>(w2,    w2_bf, H_*D_/4);

  // 2) LN1 + transpose to [B][S][D]
  ln_k<true><<<dim3(R_), 256, 0, stream>>>(x, Xn, ln1g, ln1b);

  // 3+4) XWv / Xth in one dispatch (z picks weight & dest; A shared = Xn)
  gemm256_k<0><<<dim3(R_/256, D_/256, 2), 512, 0, stream>>>(
      Xn, 0, Wv_bf, (long)D_*D_, D_, D_, XWv, (long)R_*D_, nullptr, nullptr, 0.f);

  // 5) first[b][d] = sum_n XWv[b][n][d]
  hipMemsetAsync(first, 0, B_ * D_ * sizeof(float), stream);
  colsum_k<<<dim3(D_/256, 16, B_), 256, 0, stream>>>(XWv, first);

  // 5b) transposes
  tr_k<<<dim3(D_/64, S_/64, B_), 256, 0, stream>>>(XWv, XWvT);
  tr_k<<<dim3(D_/64, S_/64, B_), 256, 0, stream>>>(Xth, XthT);

  // 6) Mt[b][e][d] = sum_n XWvT[b][e][n] * XthT[b][d][n]   (128-tile, K=4096)
  gemm_k<0><<<dim3(D_/128, D_/128, B_), 256, 0, stream>>>(
      XWvT, (long)D_*S_, XthT, (long)D_*S_, S_, D_, Mt, (long)D_*D_, nullptr, nullptr, 0.f);

  // 7) h = Xn + first/n + (1/(n*sqrt(D))) * Xn @ Mt^T -> d_out fp32 [S][B][D]
  gemm256_k<1><<<dim3(S_/256, D_/256, B_), 512, 0, stream>>>(
      Xn, (long)S_*D_, Mt, (long)D_*D_, D_, D_, nullptr, 0, out, first,
      1.0f / ((float)S_ * 32.0f));

  // 8) LN2: d_out -> h2 (bf16)
  ln_k<false><<<dim3(R_), 256, 0, stream>>>(out, h2, ln2g, ln2b);

  // 9) MLP, full M=16384
  gemm256_k<2><<<dim3(R_/256, H_/256, 1), 512, 0, stream>>>(
      h2, 0, w1_bf, 0, D_, H_, G, 0, nullptr, b1, 0.f);
  gemm256_k<3><<<dim3(R_/256, D_/256, 1), 512, 0, stream>>>(
      G, 0, w2_bf, 0, H_, D_, nullptr, 0, out, b2, 0.f);
}

// Round 7
// 566.390 us; speedup vs baseline: 1.1809x; 1.1809x over previous
//
#include <hip/hip_runtime.h>
#include <math.h>

// Problem dims (fixed by reference)
#define S_ 4096
#define B_ 4
#define D_ 1024
#define R_ (S_*B_)   // 16384 rows
#define H_ (4*D_)    // 4096

typedef unsigned short u16;
typedef unsigned int   u32;
typedef __attribute__((ext_vector_type(8))) short bf16x8;  // 8 bf16 in 4 VGPRs
typedef __attribute__((ext_vector_type(4))) float f32x4;

__device__ __forceinline__ u16 f2bf(float f) {
  u32 u = __float_as_uint(f);
  u32 r = (u + 0x7fffu + ((u >> 16) & 1u)) >> 16;   // RNE
  return (u16)r;
}
__device__ __forceinline__ float bf2f(u16 u) {
  return __uint_as_float(((u32)u) << 16);
}

// async global->LDS, 16B per lane; LDS dest is wave-uniform base + lane*16
__device__ __forceinline__ void gl_lds16(const u16* g, u16* l) {
  __builtin_amdgcn_global_load_lds((const __attribute__((address_space(1))) void*)g,
                                   (__attribute__((address_space(3))) void*)l,
                                   16, 0, 0);
}
// raw barrier with compiler memory fence (no implicit vmcnt drain)
__device__ __forceinline__ void BAR() {
  asm volatile("s_barrier" ::: "memory");
}

// fast GELU (tanh form): max |err| ~1e-3, far below bf16 quantum here.
__device__ __forceinline__ float gelu_f(float t) {
  const float u2 = 1.5957691216f * t + 0.0713548162726f * t * t * t;
  return t / (1.0f + __expf(-u2));
}

// ---------------------------------------------------------------------------
// fp32 -> bf16 convert (vector x4)
__global__ __launch_bounds__(256) void f2bf_k(const float* __restrict__ in,
                                              u16* __restrict__ out, int n4) {
  int i = blockIdx.x * 256 + threadIdx.x;
  if (i < n4) {
    float4 v = ((const float4*)in)[i];
    ushort4 o = make_ushort4(f2bf(v.x), f2bf(v.y), f2bf(v.z), f2bf(v.w));
    ((ushort4*)out)[i] = o;
  }
}

// ---------------------------------------------------------------------------
// LayerNorm over D=1024, one row per 256-thread block, 4 elems/thread.
// TR=true: input row r=(s*B+b) of x[S,B,D] -> output row (b*S+s)
template<bool TR>
__global__ __launch_bounds__(256) void ln_k(const float* __restrict__ x,
                                            u16* __restrict__ o,
                                            const float* __restrict__ g,
                                            const float* __restrict__ bb) {
  const int row = blockIdx.x;
  const int tid = threadIdx.x;
  const float4 v = *(const float4*)&x[(long)row * D_ + tid * 4];
  float vv[4] = {v.x, v.y, v.z, v.w};
  float s = vv[0] + vv[1] + vv[2] + vv[3];
  float q = vv[0]*vv[0] + vv[1]*vv[1] + vv[2]*vv[2] + vv[3]*vv[3];
  const int l = tid & 63, w = tid >> 6;
  #pragma unroll
  for (int off = 32; off > 0; off >>= 1) {
    s += __shfl_down(s, off, 64);
    q += __shfl_down(q, off, 64);
  }
  __shared__ float red[8];
  if (l == 0) { red[w] = s; red[4 + w] = q; }
  __syncthreads();
  s = red[0] + red[1] + red[2] + red[3];
  q = red[4] + red[5] + red[6] + red[7];
  const float m   = s * (1.0f / D_);
  const float var = q * (1.0f / D_) - m * m;
  const float inv = rsqrtf(var + 1e-5f);
  const long orow = TR ? ((long)(row % B_) * S_ + (row / B_)) : (long)row;
  const int j = tid * 4;
  ushort4 ou = make_ushort4(
      f2bf((vv[0] - m) * inv * g[j+0] + bb[j+0]),
      f2bf((vv[1] - m) * inv * g[j+1] + bb[j+1]),
      f2bf((vv[2] - m) * inv * g[j+2] + bb[j+2]),
      f2bf((vv[3] - m) * inv * g[j+3] + bb[j+3]));
  *(ushort4*)&o[orow * D_ + j] = ou;
}

// ---------------------------------------------------------------------------
// 128x128-tile NT GEMM (kept for Mt: per-batch 1024x1024, K=4096).
template<int EPI>
__global__ __launch_bounds__(256, 2) void gemm_k(
    const u16* __restrict__ A, long sAz,
    const u16* __restrict__ B, long sBz,
    int K, int ldc,
    u16* __restrict__ Cb, long sCz,
    float* __restrict__ Cf,
    const float* __restrict__ vec1,
    float scale)
{
  const int bz = blockIdx.z;
  const u16* Ab = A + (long)bz * sAz;
  const u16* Bb = B + (long)bz * sBz;
  const int row0 = blockIdx.x * 128;
  const int col0 = blockIdx.y * 128;
  const int lda = K;

  __shared__ __align__(16) u16 As[128 * 32];
  __shared__ __align__(16) u16 Bs[128 * 32];

  const int tid = threadIdx.x;
  const int w = tid >> 6;
  const int l = tid & 63;
  const int wr = (w >> 1) * 64;
  const int wc = (w & 1) * 64;

  f32x4 acc[4][4];
  #pragma unroll
  for (int mi = 0; mi < 4; ++mi)
    #pragma unroll
    for (int ni = 0; ni < 4; ++ni) acc[mi][ni] = (f32x4){0.f, 0.f, 0.f, 0.f};

  const int lrow = l & 15;
  const int lo   = l >> 4;

  for (int k0 = 0; k0 < K; k0 += 32) {
    __syncthreads();
    #pragma unroll
    for (int it = 0; it < 2; ++it) {
      const int cb = it * 256 + (w << 6);
      const int c  = cb + l;
      const int r  = c >> 2;
      const int qs = ((c & 3) ^ ((r >> 1) & 3)) << 3;
      gl_lds16(Ab + (long)(row0 + r) * lda + (k0 + qs), &As[cb << 3]);
      gl_lds16(Bb + (long)(col0 + r) * lda + (k0 + qs), &Bs[cb << 3]);
    }
    __syncthreads();

    bf16x8 af[4], bfr[4];
    #pragma unroll
    for (int mi = 0; mi < 4; ++mi) {
      const int R = wr + mi * 16 + lrow;
      af[mi]  = *(const bf16x8*)&As[R * 32 + ((lo ^ ((R >> 1) & 3)) << 3)];
    }
    #pragma unroll
    for (int ni = 0; ni < 4; ++ni) {
      const int R = wc + ni * 16 + lrow;
      bfr[ni] = *(const bf16x8*)&Bs[R * 32 + ((lo ^ ((R >> 1) & 3)) << 3)];
    }
    #pragma unroll
    for (int mi = 0; mi < 4; ++mi)
      #pragma unroll
      for (int ni = 0; ni < 4; ++ni)
        acc[mi][ni] = __builtin_amdgcn_mfma_f32_16x16x32_bf16(af[mi], bfr[ni], acc[mi][ni], 0, 0, 0);
  }

  const int rbase = row0 + wr + (lo << 2);
  const int cbase = col0 + wc + lrow;
  #pragma unroll
  for (int mi = 0; mi < 4; ++mi)
    #pragma unroll
    for (int ni = 0; ni < 4; ++ni)
      #pragma unroll
      for (int r = 0; r < 4; ++r) {
        const int i = rbase + mi * 16 + r;
        const int j = cbase + ni * 16;
        if constexpr (EPI == 0)
          Cb[(long)bz * sCz + (long)i * ldc + j] = f2bf(acc[mi][ni][r]);
      }
  (void)Cf; (void)vec1; (void)scale;
}

// ---------------------------------------------------------------------------
// 256x256-tile NT GEMM, BK=64, 512 threads = 8 waves (2M x 4N).
// Deep-pipelined round-4 schedule (verified 0-conflict K-loop):
//  - staging unit = one operand K-half [256 rows][32 cols] = 16 KB
//  - ring L[db][kh][op] of 8 units (128 KB LDS), counted vmcnt(8)
//  - chunk swizzle q ^ ((R>>1)&3) on both stage-source and reads
// EPI 0: bf16 C        EPI 1: attn epilogue (fp32 out [S][B][D])
// EPI 2: gelu->bf16    EPI 3: fp32 RMW accumulate (+bias)
// EPI 4: transposed bf16 write C^T[b][j][i] + fused column-sums (z==0)
template<int EPI>
__global__ __launch_bounds__(512, 2) void gemm256_k(
    const u16* __restrict__ A, long sAz,
    const u16* __restrict__ B, long sBz,
    int K, int ldc,
    u16* __restrict__ Cb, long sCz,
    float* __restrict__ Cf,
    const float* __restrict__ vec1,
    float scale)
{
  const int bz = blockIdx.z;
  const u16* Ab = A + (long)bz * sAz;
  const u16* Bb = B + (long)bz * sBz;
  const int row0 = blockIdx.x * 256;
  const int col0 = blockIdx.y * 256;

  // [dbuf][khalf][op][256*32]
  __shared__ __align__(16) u16 Lds[2][2][2][256 * 32];

  const int tid = threadIdx.x;
  const int w   = tid >> 6;       // wave 0..7
  const int l   = tid & 63;
  const int wm  = w >> 2;         // 0..1  (row half)
  const int wn  = w & 3;          // 0..3  (col quarter)
  const int lr  = l & 15;
  const int lo  = l >> 4;         // 0..3

  const int NKH = K >> 5;         // number of K-halves
  const int NT  = K >> 6;         // number of K-tiles

  const int rs   = w * 32 + (l >> 2);
  const int qsrc = ((l & 3) ^ ((l >> 3) & 3)) << 3;   // element offset

  const int qsw = (lo ^ ((lr >> 1) & 3)) << 3;

  auto STAGE = [&](int khg, int op) {
    if (khg >= NKH) return;
    const u16* src = (op ? Bb : Ab) + (long)((op ? col0 : row0) + rs) * K + khg * 32 + qsrc;
    u16* dst = &Lds[(khg >> 1) & 1][khg & 1][op][(w * 2) * 512];
    gl_lds16(src, dst);
    gl_lds16(src + (long)16 * K, dst + 512);
  };

  f32x4 acc[8][4];
  #pragma unroll
  for (int mi = 0; mi < 8; ++mi)
    #pragma unroll
    for (int ni = 0; ni < 4; ++ni) acc[mi][ni] = (f32x4){0.f, 0.f, 0.f, 0.f};

  // prologue: stage K-halves 0..2 (A,B each) = 12 loads/thread
  STAGE(0, 0); STAGE(0, 1);
  STAGE(1, 0); STAGE(1, 1);
  STAGE(2, 0); STAGE(2, 1);
  asm volatile("s_waitcnt vmcnt(8)" ::: "memory");   // A,B(0) landed
  BAR();

  for (int kt = 0; kt < NT; ++kt) {
    const u16* L00 = &Lds[kt & 1][0][0][0];  // A, kh=0
    const u16* L01 = &Lds[kt & 1][0][1][0];  // B, kh=0
    const u16* L10 = &Lds[kt & 1][1][0][0];  // A, kh=1
    const u16* L11 = &Lds[kt & 1][1][1][0];  // B, kh=1
    bf16x8 af[4], bf[4];

    // ---- phase 0: kh=0, mh=0 ----
    #pragma unroll
    for (int ni = 0; ni < 4; ++ni)
      bf[ni] = *(const bf16x8*)&L01[(wn * 64 + ni * 16 + lr) * 32 + qsw];
    #pragma unroll
    for (int mi = 0; mi < 4; ++mi)
      af[mi] = *(const bf16x8*)&L00[(wm * 128 + mi * 16 + lr) * 32 + qsw];
    STAGE(2 * kt + 3, 0);
    BAR();
    __builtin_amdgcn_s_setprio(1);
    #pragma unroll
    for (int mi = 0; mi < 4; ++mi)
      #pragma unroll
      for (int ni = 0; ni < 4; ++ni)
        acc[mi][ni] = __builtin_amdgcn_mfma_f32_16x16x32_bf16(af[mi], bf[ni], acc[mi][ni], 0, 0, 0);
    __builtin_amdgcn_s_setprio(0);
    BAR();

    // ---- phase 1: kh=0, mh=1 ----
    #pragma unroll
    for (int mi = 0; mi < 4; ++mi)
      af[mi] = *(const bf16x8*)&L00[(wm * 128 + 64 + mi * 16 + lr) * 32 + qsw];
    STAGE(2 * kt + 3, 1);
    if (kt == NT - 1) asm volatile("s_waitcnt vmcnt(0)" ::: "memory");
    else              asm volatile("s_waitcnt vmcnt(8)" ::: "memory");
    BAR();
    __builtin_amdgcn_s_setprio(1);
    #pragma unroll
    for (int mi = 0; mi < 4; ++mi)
      #pragma unroll
      for (int ni = 0; ni < 4; ++ni)
        acc[4 + mi][ni] = __builtin_amdgcn_mfma_f32_16x16x32_bf16(af[mi], bf[ni], acc[4 + mi][ni], 0, 0, 0);
    __builtin_amdgcn_s_setprio(0);
    BAR();

    // ---- phase 2: kh=1, mh=0 ----
    #pragma unroll
    for (int ni = 0; ni < 4; ++ni)
      bf[ni] = *(const bf16x8*)&L11[(wn * 64 + ni * 16 + lr) * 32 + qsw];
    #pragma unroll
    for (int mi = 0; mi < 4; ++mi)
      af[mi] = *(const bf16x8*)&L10[(wm * 128 + mi * 16 + lr) * 32 + qsw];
    STAGE(2 * kt + 4, 0);
    BAR();
    __builtin_amdgcn_s_setprio(1);
    #pragma unroll
    for (int mi = 0; mi < 4; ++mi)
      #pragma unroll
      for (int ni = 0; ni < 4; ++ni)
        acc[mi][ni] = __builtin_amdgcn_mfma_f32_16x16x32_bf16(af[mi], bf[ni], acc[mi][ni], 0, 0, 0);
    __builtin_amdgcn_s_setprio(0);
    BAR();

    // ---- phase 3: kh=1, mh=1 ----
    #pragma unroll
    for (int mi = 0; mi < 4; ++mi)
      af[mi] = *(const bf16x8*)&L10[(wm * 128 + 64 + mi * 16 + lr) * 32 + qsw];
    STAGE(2 * kt + 4, 1);
    if (kt < NT - 2)       asm volatile("s_waitcnt vmcnt(8)" ::: "memory");
    else if (kt == NT - 2) asm volatile("s_waitcnt vmcnt(4)" ::: "memory");
    else                   asm volatile("s_waitcnt vmcnt(0)" ::: "memory");
    BAR();
    __builtin_amdgcn_s_setprio(1);
    #pragma unroll
    for (int mi = 0; mi < 4; ++mi)
      #pragma unroll
      for (int ni = 0; ni < 4; ++ni)
        acc[4 + mi][ni] = __builtin_amdgcn_mfma_f32_16x16x32_bf16(af[mi], bf[ni], acc[4 + mi][ni], 0, 0, 0);
    __builtin_amdgcn_s_setprio(0);
    BAR();
  }

  if constexpr (EPI == 4) {
    // ---- fused column sums (z==0 only): first[b][d] += sum over block rows ----
    const int b = row0 / S_;                 // batch (256 | S_)
    if (bz == 0) {
      #pragma unroll
      for (int ni = 0; ni < 4; ++ni) {
        float s = 0.f;
        #pragma unroll
        for (int a = 0; a < 8; ++a)
          #pragma unroll
          for (int r = 0; r < 4; ++r) s += acc[a][ni][r];
        s += __shfl_down(s, 16, 64);
        s += __shfl_down(s, 32, 64);
        if (lo == 0) atomicAdd(&Cf[b * D_ + (col0 + wn * 64 + ni * 16 + lr)], s);
      }
    }
    // ---- transposed bf16 write: dst[b][j][i], per-wave LDS transpose ----
    // wave tile: 128 rows (i) x 64 cols (j); two passes of 64 i.
    u16* Tw = ((u16*)Lds) + w * (64 * 68);   // [64 j][68 stride]
    u16* dst = Cb + (long)bz * sCz + (long)b * D_ * S_;
    const long ib0 = (row0 % S_) + wm * 128;
    #pragma unroll
    for (int p = 0; p < 2; ++p) {
      #pragma unroll
      for (int mi = 0; mi < 4; ++mi) {
        const int a = p * 4 + mi;
        #pragma unroll
        for (int ni = 0; ni < 4; ++ni) {
          ushort4 pk = make_ushort4(f2bf(acc[a][ni][0]), f2bf(acc[a][ni][1]),
                                    f2bf(acc[a][ni][2]), f2bf(acc[a][ni][3]));
          *(ushort4*)&Tw[(ni * 16 + lr) * 68 + mi * 16 + lo * 4] = pk;
        }
      }
      #pragma unroll
      for (int it = 0; it < 8; ++it) {
        const int jj = it * 8 + (l >> 3);
        const int ic = (l & 7) * 8;
        bf16x8 v = *(const bf16x8*)&Tw[jj * 68 + ic];
        *(bf16x8*)&dst[(long)(col0 + wn * 64 + jj) * S_ + (ib0 + p * 64 + ic)] = v;
      }
    }
  } else {
    // ---- repack epilogue (coalesced wide stores) ----
    float* E = (float*)(&Lds[0][0][0][0]);
    const int wbase = w * (32 * 72);
    #pragma unroll
    for (int p = 0; p < 4; ++p) {
      #pragma unroll
      for (int mh = 0; mh < 2; ++mh) {
        const int a = ((p >> 1) << 2) + ((p & 1) << 1) + mh;
        #pragma unroll
        for (int ni = 0; ni < 4; ++ni)
          #pragma unroll
          for (int r = 0; r < 4; ++r)
            E[wbase + (mh * 16 + lo * 4 + r) * 72 + ni * 16 + lr] = acc[a][ni][r];
      }
      #pragma unroll
      for (int rr = 0; rr < 8; ++rr) {
        const int rl = (l >> 4) + rr * 4;        // 0..31 within pass
        const int cl = (l & 15) * 4;             // 0..60
        const f32x4 v = *(const f32x4*)&E[wbase + rl * 72 + cl];
        const long i = row0 + wm * 128 + p * 32 + rl;
        const int  j = col0 + wn * 64 + cl;
        if constexpr (EPI == 0) {
          ushort4 o = make_ushort4(f2bf(v[0]), f2bf(v[1]), f2bf(v[2]), f2bf(v[3]));
          *(ushort4*)&Cb[(long)bz * sCz + i * ldc + j] = o;
        } else if constexpr (EPI == 1) {
          const ushort4 xv = *(const ushort4*)&Ab[i * K + j];   // K == D_ here
          const f32x4 f1 = *(const f32x4*)&vec1[bz * D_ + j];
          f32x4 o;
          o[0] = bf2f(xv.x) + f1[0] * (1.0f / S_) + scale * v[0];
          o[1] = bf2f(xv.y) + f1[1] * (1.0f / S_) + scale * v[1];
          o[2] = bf2f(xv.z) + f1[2] * (1.0f / S_) + scale * v[2];
          o[3] = bf2f(xv.w) + f1[3] * (1.0f / S_) + scale * v[3];
          *(f32x4*)&Cf[(i * B_ + bz) * (long)D_ + j] = o;
        } else if constexpr (EPI == 2) {
          const f32x4 b = *(const f32x4*)&vec1[j];
          ushort4 o = make_ushort4(f2bf(gelu_f(v[0] + b[0])),
                                   f2bf(gelu_f(v[1] + b[1])),
                                   f2bf(gelu_f(v[2] + b[2])),
                                   f2bf(gelu_f(v[3] + b[3])));
          *(ushort4*)&Cb[i * ldc + j] = o;
        } else {
          const f32x4 b = *(const f32x4*)&vec1[j];
          f32x4 c = *(const f32x4*)&Cf[i * ldc + j];
          c[0] += v[0] + b[0]; c[1] += v[1] + b[1];
          c[2] += v[2] + b[2]; c[3] += v[3] + b[3];
          *(f32x4*)&Cf[i * ldc + j] = c;
        }
      }
    }
  }
}

// ---------------------------------------------------------------------------
extern "C" void kernel_launch(void* const* d_in, const int* in_sizes, int n_in,
                              void* d_out, int out_size, void* d_ws, size_t ws_size,
                              hipStream_t stream) {
  (void)in_sizes; (void)n_in; (void)out_size; (void)ws_size;
  const float* x     = (const float*)d_in[0];
  const float* W_v   = (const float*)d_in[1];
  const float* theta = (const float*)d_in[2];
  const float* ln1g  = (const float*)d_in[3];
  const float* ln1b  = (const float*)d_in[4];
  const float* ln2g  = (const float*)d_in[5];
  const float* ln2b  = (const float*)d_in[6];
  const float* w1    = (const float*)d_in[7];
  const float* b1    = (const float*)d_in[8];
  const float* w2    = (const float*)d_in[9];
  const float* b2    = (const float*)d_in[10];
  float* out = (float*)d_out;

  char* ws = (char*)d_ws;
  const size_t MB = 1024ull * 1024ull;
  u16*   Wv_bf = (u16*)(ws + 0);              //  2 MB   (Th follows contiguously)
  u16*   Th_bf = (u16*)(ws + 2 * MB);         //  2 MB
  u16*   w1_bf = (u16*)(ws + 4 * MB);         //  8 MB
  u16*   w2_bf = (u16*)(ws + 12 * MB);        //  8 MB
  float* first = (float*)(ws + 20 * MB);      // 16 KB
  u16*   Mt    = (u16*)(ws + 21 * MB);        //  8 MB  Mt[b][e][d] = M[b][d][e]
  u16*   Xn    = (u16*)(ws + 29 * MB);        // 32 MB  [B][S][D] (LN1 out, transposed)
  u16*   XWvT  = (u16*)(ws + 61 * MB);        // 32 MB  [B][D][S]  (XthT contiguous after)
  u16*   XthT  = (u16*)(ws + 93 * MB);        // 32 MB  [B][D][S]  (ends 125 MB)
  u16*   h2    = (u16*)(ws + 29 * MB);        // 32 MB  (over dead Xn, after EPI1)
  u16*   G     = (u16*)(ws + 61 * MB);        // 128 MB [16384][4096] (over dead XWvT/XthT)

  // 1) weights -> bf16
  f2bf_k<<<dim3((D_*D_/4 + 255)/256), 256, 0, stream>>>(W_v,   Wv_bf, D_*D_/4);
  f2bf_k<<<dim3((D_*D_/4 + 255)/256), 256, 0, stream>>>(theta, Th_bf, D_*D_/4);
  f2bf_k<<<dim3((H_*D_/4 + 255)/256), 256, 0, stream>>>(w1,    w1_bf, H_*D_/4);
  f2bf_k<<<dim3((H_*D_/4 + 255)/256), 256, 0, stream>>>(w2,    w2_bf, H_*D_/4);

  // 2) LN1 + transpose to [B][S][D]
  ln_k<true><<<dim3(R_), 256, 0, stream>>>(x, Xn, ln1g, ln1b);

  // 3) XWvT / XthT in one dispatch (z picks weight & dest), transposed write
  //    + fused column-sums into `first` (z==0)
  hipMemsetAsync(first, 0, B_ * D_ * sizeof(float), stream);
  gemm256_k<4><<<dim3(R_/256, D_/256, 2), 512, 0, stream>>>(
      Xn, 0, Wv_bf, (long)D_*D_, D_, D_,
      XWvT, (long)D_*S_*B_, first, nullptr, 0.f);

  // 4) Mt[b][e][d] = sum_n XWvT[b][e][n] * XthT[b][d][n]   (128-tile, K=4096)
  gemm_k<0><<<dim3(D_/128, D_/128, B_), 256, 0, stream>>>(
      XWvT, (long)D_*S_, XthT, (long)D_*S_, S_, D_, Mt, (long)D_*D_, nullptr, nullptr, 0.f);

  // 5) h = Xn + first/n + (1/(n*sqrt(D))) * Xn @ Mt^T -> d_out fp32 [S][B][D]
  gemm256_k<1><<<dim3(S_/256, D_/256, B_), 512, 0, stream>>>(
      Xn, (long)S_*D_, Mt, (long)D_*D_, D_, D_, nullptr, 0, out, first,
      1.0f / ((float)S_ * 32.0f));

  // 6) LN2: d_out -> h2 (bf16)
  ln_k<false><<<dim3(R_), 256, 0, stream>>>(out, h2, ln2g, ln2b);

  // 7) MLP, full M=16384
  gemm256_k<2><<<dim3(R_/256, H_/256, 1), 512, 0, stream>>>(
      h2, 0, w1_bf, 0, D_, H_, G, 0, nullptr, b1, 0.f);
  gemm256_k<3><<<dim3(R_/256, D_/256, 1), 512, 0, stream>>>(
      G, 0, w2_bf, 0, H_, D_, nullptr, 0, out, b2, 0.f);
}

// Round 8
// 557.584 us; speedup vs baseline: 1.1996x; 1.0158x over previous
//
#include <hip/hip_runtime.h>
#include <math.h>

// Problem dims (fixed by reference)
#define S_ 4096
#define B_ 4
#define D_ 1024
#define R_ (S_*B_)   // 16384 rows
#define H_ (4*D_)    // 4096

typedef unsigned short u16;
typedef unsigned int   u32;
typedef __attribute__((ext_vector_type(8))) short bf16x8;  // 8 bf16 in 4 VGPRs
typedef __attribute__((ext_vector_type(4))) float f32x4;

__device__ __forceinline__ u16 f2bf(float f) {
  u32 u = __float_as_uint(f);
  u32 r = (u + 0x7fffu + ((u >> 16) & 1u)) >> 16;   // RNE
  return (u16)r;
}
__device__ __forceinline__ float bf2f(u16 u) {
  return __uint_as_float(((u32)u) << 16);
}

// async global->LDS, 16B per lane; LDS dest is wave-uniform base + lane*16
__device__ __forceinline__ void gl_lds16(const u16* g, u16* l) {
  __builtin_amdgcn_global_load_lds((const __attribute__((address_space(1))) void*)g,
                                   (__attribute__((address_space(3))) void*)l,
                                   16, 0, 0);
}
// raw barrier with compiler memory fence (no implicit vmcnt drain)
__device__ __forceinline__ void BAR() {
  asm volatile("s_barrier" ::: "memory");
}
#define VM(N) asm volatile("s_waitcnt vmcnt(" #N ")" ::: "memory")

// fast GELU (tanh form): max |err| ~1e-3, far below bf16 quantum here.
__device__ __forceinline__ float gelu_f(float t) {
  const float u2 = 1.5957691216f * t + 0.0713548162726f * t * t * t;
  return t / (1.0f + __expf(-u2));
}

// 16-MFMA cluster with setprio
__device__ __forceinline__ void mfma16(const bf16x8* af, const bf16x8* bfr, f32x4* a) {
  __builtin_amdgcn_s_setprio(1);
  #pragma unroll
  for (int mi = 0; mi < 4; ++mi)
    #pragma unroll
    for (int ni = 0; ni < 4; ++ni)
      a[mi*4+ni] = __builtin_amdgcn_mfma_f32_16x16x32_bf16(af[mi], bfr[ni], a[mi*4+ni], 0, 0, 0);
  __builtin_amdgcn_s_setprio(0);
}

// ---------------------------------------------------------------------------
// fp32 -> bf16 convert (vector x4)
__global__ __launch_bounds__(256) void f2bf_k(const float* __restrict__ in,
                                              u16* __restrict__ out, int n4) {
  int i = blockIdx.x * 256 + threadIdx.x;
  if (i < n4) {
    float4 v = ((const float4*)in)[i];
    ushort4 o = make_ushort4(f2bf(v.x), f2bf(v.y), f2bf(v.z), f2bf(v.w));
    ((ushort4*)out)[i] = o;
  }
}

// ---------------------------------------------------------------------------
// LayerNorm over D=1024, one row per 256-thread block, 4 elems/thread.
// TR=true: input row r=(s*B+b) of x[S,B,D] -> output row (b*S+s)
template<bool TR>
__global__ __launch_bounds__(256) void ln_k(const float* __restrict__ x,
                                            u16* __restrict__ o,
                                            const float* __restrict__ g,
                                            const float* __restrict__ bb) {
  const int row = blockIdx.x;
  const int tid = threadIdx.x;
  const float4 v = *(const float4*)&x[(long)row * D_ + tid * 4];
  float vv[4] = {v.x, v.y, v.z, v.w};
  float s = vv[0] + vv[1] + vv[2] + vv[3];
  float q = vv[0]*vv[0] + vv[1]*vv[1] + vv[2]*vv[2] + vv[3]*vv[3];
  const int l = tid & 63, w = tid >> 6;
  #pragma unroll
  for (int off = 32; off > 0; off >>= 1) {
    s += __shfl_down(s, off, 64);
    q += __shfl_down(q, off, 64);
  }
  __shared__ float red[8];
  if (l == 0) { red[w] = s; red[4 + w] = q; }
  __syncthreads();
  s = red[0] + red[1] + red[2] + red[3];
  q = red[4] + red[5] + red[6] + red[7];
  const float m   = s * (1.0f / D_);
  const float var = q * (1.0f / D_) - m * m;
  const float inv = rsqrtf(var + 1e-5f);
  const long orow = TR ? ((long)(row % B_) * S_ + (row / B_)) : (long)row;
  const int j = tid * 4;
  ushort4 ou = make_ushort4(
      f2bf((vv[0] - m) * inv * g[j+0] + bb[j+0]),
      f2bf((vv[1] - m) * inv * g[j+1] + bb[j+1]),
      f2bf((vv[2] - m) * inv * g[j+2] + bb[j+2]),
      f2bf((vv[3] - m) * inv * g[j+3] + bb[j+3]));
  *(ushort4*)&o[orow * D_ + j] = ou;
}

// ---------------------------------------------------------------------------
// 128x128-tile NT GEMM (kept for Mt: per-batch 1024x1024, K=4096).
template<int EPI>
__global__ __launch_bounds__(256, 2) void gemm_k(
    const u16* __restrict__ A, long sAz,
    const u16* __restrict__ B, long sBz,
    int K, int ldc,
    u16* __restrict__ Cb, long sCz,
    float* __restrict__ Cf,
    const float* __restrict__ vec1,
    float scale)
{
  const int bz = blockIdx.z;
  const u16* Ab = A + (long)bz * sAz;
  const u16* Bb = B + (long)bz * sBz;
  const int row0 = blockIdx.x * 128;
  const int col0 = blockIdx.y * 128;
  const int lda = K;

  __shared__ __align__(16) u16 As[128 * 32];
  __shared__ __align__(16) u16 Bs[128 * 32];

  const int tid = threadIdx.x;
  const int w = tid >> 6;
  const int l = tid & 63;
  const int wr = (w >> 1) * 64;
  const int wc = (w & 1) * 64;

  f32x4 acc[4][4];
  #pragma unroll
  for (int mi = 0; mi < 4; ++mi)
    #pragma unroll
    for (int ni = 0; ni < 4; ++ni) acc[mi][ni] = (f32x4){0.f, 0.f, 0.f, 0.f};

  const int lrow = l & 15;
  const int lo   = l >> 4;

  for (int k0 = 0; k0 < K; k0 += 32) {
    __syncthreads();
    #pragma unroll
    for (int it = 0; it < 2; ++it) {
      const int cb = it * 256 + (w << 6);
      const int c  = cb + l;
      const int r  = c >> 2;
      const int qs = ((c & 3) ^ ((r >> 1) & 3)) << 3;
      gl_lds16(Ab + (long)(row0 + r) * lda + (k0 + qs), &As[cb << 3]);
      gl_lds16(Bb + (long)(col0 + r) * lda + (k0 + qs), &Bs[cb << 3]);
    }
    __syncthreads();

    bf16x8 af[4], bfr[4];
    #pragma unroll
    for (int mi = 0; mi < 4; ++mi) {
      const int R = wr + mi * 16 + lrow;
      af[mi]  = *(const bf16x8*)&As[R * 32 + ((lo ^ ((R >> 1) & 3)) << 3)];
    }
    #pragma unroll
    for (int ni = 0; ni < 4; ++ni) {
      const int R = wc + ni * 16 + lrow;
      bfr[ni] = *(const bf16x8*)&Bs[R * 32 + ((lo ^ ((R >> 1) & 3)) << 3)];
    }
    #pragma unroll
    for (int mi = 0; mi < 4; ++mi)
      #pragma unroll
      for (int ni = 0; ni < 4; ++ni)
        acc[mi][ni] = __builtin_amdgcn_mfma_f32_16x16x32_bf16(af[mi], bfr[ni], acc[mi][ni], 0, 0, 0);
  }

  const int rbase = row0 + wr + (lo << 2);
  const int cbase = col0 + wc + lrow;
  #pragma unroll
  for (int mi = 0; mi < 4; ++mi)
    #pragma unroll
    for (int ni = 0; ni < 4; ++ni)
      #pragma unroll
      for (int r = 0; r < 4; ++r) {
        const int i = rbase + mi * 16 + r;
        const int j = cbase + ni * 16;
        if constexpr (EPI == 0)
          Cb[(long)bz * sCz + (long)i * ldc + j] = f2bf(acc[mi][ni][r]);
      }
  (void)Cf; (void)vec1; (void)scale;
}

// ---------------------------------------------------------------------------
// 256x256-tile NT GEMM, BK=64, 512 threads = 8 waves (2M x 4N).
// Round-4 pipeline (counted vmcnt(8) ring), now with zero-VALU hot loop:
// LDS units laid out [op][db][kh] (16 KB units) so every ds_read_b128 is
// base VGPR + compile-time offset; K-loop unrolled x2 (cur literal);
// STAGE via running global pointers (+256 B / double-iter).
// ACC(A,NI): A in 0..7 = mh*4+mi rows wm*128 + (A>>2)*64 + (A&3)*16.
#define ACC(A_, NI_) acc[(((A_) >> 2) << 4) + (((A_) & 3) << 2) + (NI_)]

#define RD_B(CUR, KH) \
  bfr[0] = *(const bf16x8*)(pB + (CUR)*16384 + (KH)*8192 + 0);    \
  bfr[1] = *(const bf16x8*)(pB + (CUR)*16384 + (KH)*8192 + 512);  \
  bfr[2] = *(const bf16x8*)(pB + (CUR)*16384 + (KH)*8192 + 1024); \
  bfr[3] = *(const bf16x8*)(pB + (CUR)*16384 + (KH)*8192 + 1536);

#define RD_A(CUR, KH, MH) \
  af[0] = *(const bf16x8*)(pA + (CUR)*16384 + (KH)*8192 + (MH)*2048 + 0);    \
  af[1] = *(const bf16x8*)(pA + (CUR)*16384 + (KH)*8192 + (MH)*2048 + 512);  \
  af[2] = *(const bf16x8*)(pA + (CUR)*16384 + (KH)*8192 + (MH)*2048 + 1024); \
  af[3] = *(const bf16x8*)(pA + (CUR)*16384 + (KH)*8192 + (MH)*2048 + 1536);

#define STG(OP, KREL) \
  if (4 * kt2 + (KREL) < NKH) { \
    const u16* s_ = (OP ? pGB : pGA) + (KREL) * 32; \
    u16* d_ = LdsFu + (OP)*32768 + ((((KREL) >> 1) & 1))*16384 + (((KREL) & 1))*8192 + wst; \
    gl_lds16(s_, d_); \
    gl_lds16(s_ + gK16, d_ + 512); \
  }

#define ITER(CUR) { \
    const int kt = 2 * kt2 + (CUR); \
    RD_B(CUR, 0) RD_A(CUR, 0, 0) \
    STG(0, 3 + 2*(CUR)) \
    BAR(); \
    mfma16(af, bfr, acc); \
    BAR(); \
    RD_A(CUR, 0, 1) \
    STG(1, 3 + 2*(CUR)) \
    if (kt == NT - 1) { VM(0); } else { VM(8); } \
    BAR(); \
    mfma16(af, bfr, acc + 16); \
    BAR(); \
    RD_B(CUR, 1) RD_A(CUR, 1, 0) \
    STG(0, 4 + 2*(CUR)) \
    BAR(); \
    mfma16(af, bfr, acc); \
    BAR(); \
    RD_A(CUR, 1, 1) \
    STG(1, 4 + 2*(CUR)) \
    if (kt < NT - 2) { VM(8); } else if (kt == NT - 2) { VM(4); } else { VM(0); } \
    BAR(); \
    mfma16(af, bfr, acc + 16); \
    BAR(); \
  }

template<int EPI>
__global__ __launch_bounds__(512, 1) void gemm256_k(
    const u16* __restrict__ A, long sAz,
    const u16* __restrict__ B, long sBz,
    int K, int ldc,
    u16* __restrict__ Cb, long sCz,
    float* __restrict__ Cf,
    const float* __restrict__ vec1,
    float scale)
{
  const int bz = blockIdx.z;
  const u16* Ab = A + (long)bz * sAz;
  const u16* Bb = B + (long)bz * sBz;
  const int row0 = blockIdx.x * 256;
  const int col0 = blockIdx.y * 256;

  // 8 units of 16 KB, layout [op][db][kh]
  __shared__ __align__(16) u16 LdsFu[8 * 256 * 32];

  const int tid = threadIdx.x;
  const int w   = tid >> 6;       // wave 0..7
  const int l   = tid & 63;
  const int wm  = w >> 2;         // 0..1  (row half)
  const int wn  = w & 3;          // 0..3  (col quarter)
  const int lr  = l & 15;
  const int lo  = l >> 4;         // 0..3

  const int NKH = K >> 5;         // number of K-halves
  const int NT  = K >> 6;         // number of K-tiles (even)

  const int rs   = w * 32 + (l >> 2);
  const int qsrc = ((l & 3) ^ ((l >> 3) & 3)) << 3;   // element offset
  const int qsw  = (lo ^ ((lr >> 1) & 3)) << 3;
  const int wst  = w * 1024;                          // stage LDS dest (u16)
  const long gK16 = (long)16 * K;                     // +16 rows (elements)

  // loop-invariant read bases (u16 offsets)
  const u16* pA = LdsFu + (wm * 128 + lr) * 32 + qsw;
  const u16* pB = LdsFu + 32768 + (wn * 64 + lr) * 32 + qsw;
  // running stage source pointers
  const u16* pGA = Ab + (long)(row0 + rs) * K + qsrc;
  const u16* pGB = Bb + (long)(col0 + rs) * K + qsrc;

  f32x4 acc[32];
  #pragma unroll
  for (int i = 0; i < 32; ++i) acc[i] = (f32x4){0.f, 0.f, 0.f, 0.f};

  // prologue: stage K-halves 0..2 (A,B each) = 12 loads/thread
  {
    auto PSTG = [&](int khg, int op) {
      if (khg >= NKH) return;
      const u16* s = (op ? pGB : pGA) + khg * 32;
      u16* d = LdsFu + op * 32768 + ((khg >> 1) & 1) * 16384 + (khg & 1) * 8192 + wst;
      gl_lds16(s, d);
      gl_lds16(s + gK16, d + 512);
    };
    PSTG(0, 0); PSTG(0, 1);
    PSTG(1, 0); PSTG(1, 1);
    PSTG(2, 0); PSTG(2, 1);
  }
  VM(8);   // A,B of K-half 0 landed
  BAR();

  {
    bf16x8 af[4], bfr[4];
    const int NT2 = NT >> 1;
    for (int kt2 = 0; kt2 < NT2; ++kt2) {
      ITER(0)
      ITER(1)
      pGA += 128;
      pGB += 128;
    }
  }

  if constexpr (EPI == 4) {
    // ---- fused column sums (z==0 only) + transposed bf16 write ----
    const int b = row0 / S_;                 // batch (256 | S_)
    if (bz == 0) {
      #pragma unroll
      for (int ni = 0; ni < 4; ++ni) {
        float s = 0.f;
        #pragma unroll
        for (int a = 0; a < 8; ++a)
          #pragma unroll
          for (int r = 0; r < 4; ++r) s += ACC(a, ni)[r];
        s += __shfl_down(s, 16, 64);
        s += __shfl_down(s, 32, 64);
        if (lo == 0) atomicAdd(&Cf[b * D_ + (col0 + wn * 64 + ni * 16 + lr)], s);
      }
    }
    u16* Tw = LdsFu + w * (64 * 68);   // [64 j][68 stride]
    u16* dst = Cb + (long)bz * sCz + (long)b * D_ * S_;
    const long ib0 = (row0 % S_) + wm * 128;
    #pragma unroll
    for (int p = 0; p < 2; ++p) {
      #pragma unroll
      for (int mi = 0; mi < 4; ++mi) {
        const int a = p * 4 + mi;
        #pragma unroll
        for (int ni = 0; ni < 4; ++ni) {
          ushort4 pk = make_ushort4(f2bf(ACC(a, ni)[0]), f2bf(ACC(a, ni)[1]),
                                    f2bf(ACC(a, ni)[2]), f2bf(ACC(a, ni)[3]));
          *(ushort4*)&Tw[(ni * 16 + lr) * 68 + mi * 16 + lo * 4] = pk;
        }
      }
      #pragma unroll
      for (int it = 0; it < 8; ++it) {
        const int jj = it * 8 + (l >> 3);
        const int ic = (l & 7) * 8;
        bf16x8 v = *(const bf16x8*)&Tw[jj * 68 + ic];
        *(bf16x8*)&dst[(long)(col0 + wn * 64 + jj) * S_ + (ib0 + p * 64 + ic)] = v;
      }
    }
  } else {
    // ---- repack epilogue (coalesced wide stores) ----
    float* E = (float*)LdsFu;
    const int wbase = w * (32 * 72);
    #pragma unroll
    for (int p = 0; p < 4; ++p) {
      #pragma unroll
      for (int mh = 0; mh < 2; ++mh) {
        const int a = ((p >> 1) << 2) + ((p & 1) << 1) + mh;
        #pragma unroll
        for (int ni = 0; ni < 4; ++ni)
          #pragma unroll
          for (int r = 0; r < 4; ++r)
            E[wbase + (mh * 16 + lo * 4 + r) * 72 + ni * 16 + lr] = ACC(a, ni)[r];
      }
      #pragma unroll
      for (int rr = 0; rr < 8; ++rr) {
        const int rl = (l >> 4) + rr * 4;        // 0..31 within pass
        const int cl = (l & 15) * 4;             // 0..60
        const f32x4 v = *(const f32x4*)&E[wbase + rl * 72 + cl];
        const long i = row0 + wm * 128 + p * 32 + rl;
        const int  j = col0 + wn * 64 + cl;
        if constexpr (EPI == 0) {
          ushort4 o = make_ushort4(f2bf(v[0]), f2bf(v[1]), f2bf(v[2]), f2bf(v[3]));
          *(ushort4*)&Cb[(long)bz * sCz + i * ldc + j] = o;
        } else if constexpr (EPI == 1) {
          const ushort4 xv = *(const ushort4*)&Ab[i * K + j];   // K == D_ here
          const f32x4 f1 = *(const f32x4*)&vec1[bz * D_ + j];
          f32x4 o;
          o[0] = bf2f(xv.x) + f1[0] * (1.0f / S_) + scale * v[0];
          o[1] = bf2f(xv.y) + f1[1] * (1.0f / S_) + scale * v[1];
          o[2] = bf2f(xv.z) + f1[2] * (1.0f / S_) + scale * v[2];
          o[3] = bf2f(xv.w) + f1[3] * (1.0f / S_) + scale * v[3];
          *(f32x4*)&Cf[(i * B_ + bz) * (long)D_ + j] = o;
        } else if constexpr (EPI == 2) {
          const f32x4 b = *(const f32x4*)&vec1[j];
          ushort4 o = make_ushort4(f2bf(gelu_f(v[0] + b[0])),
                                   f2bf(gelu_f(v[1] + b[1])),
                                   f2bf(gelu_f(v[2] + b[2])),
                                   f2bf(gelu_f(v[3] + b[3])));
          *(ushort4*)&Cb[i * ldc + j] = o;
        } else {
          const f32x4 b = *(const f32x4*)&vec1[j];
          f32x4 c = *(const f32x4*)&Cf[i * ldc + j];
          c[0] += v[0] + b[0]; c[1] += v[1] + b[1];
          c[2] += v[2] + b[2]; c[3] += v[3] + b[3];
          *(f32x4*)&Cf[i * ldc + j] = c;
        }
      }
    }
  }
}

// ---------------------------------------------------------------------------
extern "C" void kernel_launch(void* const* d_in, const int* in_sizes, int n_in,
                              void* d_out, int out_size, void* d_ws, size_t ws_size,
                              hipStream_t stream) {
  (void)in_sizes; (void)n_in; (void)out_size; (void)ws_size;
  const float* x     = (const float*)d_in[0];
  const float* W_v   = (const float*)d_in[1];
  const float* theta = (const float*)d_in[2];
  const float* ln1g  = (const float*)d_in[3];
  const float* ln1b  = (const float*)d_in[4];
  const float* ln2g  = (const float*)d_in[5];
  const float* ln2b  = (const float*)d_in[6];
  const float* w1    = (const float*)d_in[7];
  const float* b1    = (const float*)d_in[8];
  const float* w2    = (const float*)d_in[9];
  const float* b2    = (const float*)d_in[10];
  float* out = (float*)d_out;

  char* ws = (char*)d_ws;
  const size_t MB = 1024ull * 1024ull;
  u16*   Wv_bf = (u16*)(ws + 0);              //  2 MB   (Th follows contiguously)
  u16*   Th_bf = (u16*)(ws + 2 * MB);         //  2 MB
  u16*   w1_bf = (u16*)(ws + 4 * MB);         //  8 MB
  u16*   w2_bf = (u16*)(ws + 12 * MB);        //  8 MB
  float* first = (float*)(ws + 20 * MB);      // 16 KB
  u16*   Mt    = (u16*)(ws + 21 * MB);        //  8 MB  Mt[b][e][d] = M[b][d][e]
  u16*   Xn    = (u16*)(ws + 29 * MB);        // 32 MB  [B][S][D] (LN1 out, transposed)
  u16*   XWvT  = (u16*)(ws + 61 * MB);        // 32 MB  [B][D][S]  (XthT contiguous after)
  u16*   XthT  = (u16*)(ws + 93 * MB);        // 32 MB  [B][D][S]  (ends 125 MB)
  u16*   h2    = (u16*)(ws + 29 * MB);        // 32 MB  (over dead Xn, after EPI1)
  u16*   G     = (u16*)(ws + 61 * MB);        // 128 MB [16384][4096] (over dead XWvT/XthT)

  // 1) weights -> bf16
  f2bf_k<<<dim3((D_*D_/4 + 255)/256), 256, 0, stream>>>(W_v,   Wv_bf, D_*D_/4);
  f2bf_k<<<dim3((D_*D_/4 + 255)/256), 256, 0, stream>>>(theta, Th_bf, D_*D_/4);
  f2bf_k<<<dim3((H_*D_/4 + 255)/256), 256, 0, stream>>>(w1,    w1_bf, H_*D_/4);
  f2bf_k<<<dim3((H_*D_/4 + 255)/256), 256, 0, stream>>>(w2,    w2_bf, H_*D_/4);

  // 2) LN1 + transpose to [B][S][D]
  ln_k<true><<<dim3(R_), 256, 0, stream>>>(x, Xn, ln1g, ln1b);

  // 3) XWvT / XthT in one dispatch (z picks weight & dest), transposed write
  //    + fused column-sums into `first` (z==0)
  hipMemsetAsync(first, 0, B_ * D_ * sizeof(float), stream);
  gemm256_k<4><<<dim3(R_/256, D_/256, 2), 512, 0, stream>>>(
      Xn, 0, Wv_bf, (long)D_*D_, D_, D_,
      XWvT, (long)D_*S_*B_, first, nullptr, 0.f);

  // 4) Mt[b][e][d] = sum_n XWvT[b][e][n] * XthT[b][d][n]   (128-tile, K=4096)
  gemm_k<0><<<dim3(D_/128, D_/128, B_), 256, 0, stream>>>(
      XWvT, (long)D_*S_, XthT, (long)D_*S_, S_, D_, Mt, (long)D_*D_, nullptr, nullptr, 0.f);

  // 5) h = Xn + first/n + (1/(n*sqrt(D))) * Xn @ Mt^T -> d_out fp32 [S][B][D]
  gemm256_k<1><<<dim3(S_/256, D_/256, B_), 512, 0, stream>>>(
      Xn, (long)S_*D_, Mt, (long)D_*D_, D_, D_, nullptr, 0, out, first,
      1.0f / ((float)S_ * 32.0f));

  // 6) LN2: d_out -> h2 (bf16)
  ln_k<false><<<dim3(R_), 256, 0, stream>>>(out, h2, ln2g, ln2b);

  // 7) MLP, full M=16384
  gemm256_k<2><<<dim3(R_/256, H_/256, 1), 512, 0, stream>>>(
      h2, 0, w1_bf, 0, D_, H_, G, 0, nullptr, b1, 0.f);
  gemm256_k<3><<<dim3(R_/256, D_/256, 1), 512, 0, stream>>>(
      G, 0, w2_bf, 0, H_, D_, nullptr, 0, out, b2, 0.f);
}